// Round 3
// baseline (270.955 us; speedup 1.0000x reference)
//
#include <hip/hip_runtime.h>
#include <math.h>

// Problem constants: B=8, S=128, V=32000, K=32.
constexpr int Bc = 8, Sc = 128, Vc = 32000, Kc = 32;
constexpr int ROWS = Bc * Sc;        // 1024
constexpr int V4 = Vc / 4;           // 8000 float4 per row
constexpr int NTA = 256;             // threads, kernel A
constexpr int NTB = 256;             // threads, kernel B
constexpr int CHUNKS = 4;            // chunks per row, kernel B
constexpr int CHUNK_F4 = V4 / CHUNKS;// 2000 float4 per chunk

// Native vector type: __builtin_nontemporal_store requires a scalar/native
// vector, not HIP's float4 class.
typedef float v4f __attribute__((ext_vector_type(4)));

// ---------------- Kernel A: per-row online-softmax reduction ----------------
// One 256-thread block per row. Single streaming read of the row; online
// (m, s) per thread (exp rescale hidden under load latency). Writes
// ws[2*row] = M, ws[2*row+1] = cn/Z  where cn = (1-ol)*om + (1-cl)*cm.
__global__ __launch_bounds__(NTA) void knn_reduce_kernel(
    const float* __restrict__ logit,
    const int*   __restrict__ prev_words,
    const float* __restrict__ optor_lamda,
    const float* __restrict__ const_lamda,
    float* __restrict__ ws)
{
    const int row = blockIdx.x;
    const int t   = threadIdx.x;
    const v4f* __restrict__ x = (const v4f*)(logit + (size_t)row * Vc);

    float m = -INFINITY, s = 0.f;
#pragma unroll 4
    for (int i = t; i < V4; i += NTA) {
        const v4f v = x[i];
        const float m4 = fmaxf(fmaxf(v.x, v.y), fmaxf(v.z, v.w));
        const float mn = fmaxf(m, m4);
        s = s * __expf(m - mn)
          + __expf(v.x - mn) + __expf(v.y - mn)
          + __expf(v.z - mn) + __expf(v.w - mn);
        m = mn;
    }
    // wave reduce (m,s) pairs
#pragma unroll
    for (int off = 32; off > 0; off >>= 1) {
        const float m2 = __shfl_xor(m, off);
        const float s2 = __shfl_xor(s, off);
        const float mn = fmaxf(m, m2);
        s = s * __expf(m - mn) + s2 * __expf(m2 - mn);
        m = mn;
    }
    __shared__ float rm[NTA / 64], rs[NTA / 64];
    const int wave = t >> 6;
    if ((t & 63) == 0) { rm[wave] = m; rs[wave] = s; }
    __syncthreads();
    if (t == 0) {
        float M = rm[0];
#pragma unroll
        for (int w = 1; w < NTA / 64; ++w) M = fmaxf(M, rm[w]);
        float Z = 0.f;
#pragma unroll
        for (int w = 0; w < NTA / 64; ++w) Z += rs[w] * __expf(rm[w] - M);

        const int pw = prev_words[row];
        const bool om = (pw <= 88) || (pw >= 91 && pw <= 291);
        const bool cm = (pw == 89) || (pw == 90) || (pw >= 292);
        const float cn = (1.f - optor_lamda[0]) * (om ? 1.f : 0.f)
                       + (1.f - const_lamda[0]) * (cm ? 1.f : 0.f);
        ws[2 * row]     = M;
        ws[2 * row + 1] = cn / Z;
    }
}

// ---------------- Kernel B: streaming map out = exp(x - M) * (cn/Z) --------
// grid (1024 rows, 4 chunks) x 256 threads. Non-temporal stores keep the
// logit resident in L3 for our own (L3-hot) reads.
__global__ __launch_bounds__(NTB) void knn_map_kernel(
    const float* __restrict__ logit,
    const float* __restrict__ ws,
    float* __restrict__ out)
{
    const int row = blockIdx.x;
    const int t   = threadIdx.x;
    const float M  = ws[2 * row];
    const float sc = ws[2 * row + 1];
    const size_t base4 = (size_t)row * V4;
    const v4f* __restrict__ x = (const v4f*)logit + base4;
    v4f* __restrict__       o = (v4f*)out + base4;
    const int begin = blockIdx.y * CHUNK_F4;
    const int end   = begin + CHUNK_F4;
#pragma unroll 4
    for (int i = begin + t; i < end; i += NTB) {
        v4f v = x[i];
        v.x = __expf(v.x - M) * sc;
        v.y = __expf(v.y - M) * sc;
        v.z = __expf(v.z - M) * sc;
        v.w = __expf(v.w - M) * sc;
        __builtin_nontemporal_store(v, &o[i]);
    }
}

// ---------------- Kernel C: kNN softmax scatter -----------------------------
// One 64-thread block per row: lanes 0..31 optor, 32..63 const.
__global__ __launch_bounds__(64) void knn_scatter_kernel(
    const int*   __restrict__ optor_vals,
    const float* __restrict__ optor_dists,
    const int*   __restrict__ const_vals,
    const float* __restrict__ const_dists,
    const int*   __restrict__ prev_words,
    const float* __restrict__ optor_lamda,
    const float* __restrict__ const_lamda,
    const float* __restrict__ optor_temp,
    const float* __restrict__ const_temp,
    float* __restrict__ out)
{
    const int row = blockIdx.x;
    const int t   = threadIdx.x;
    const bool is_opt = (t < 32);
    const int k = t & 31;

    const int pw = prev_words[row];
    const bool om = (pw <= 88) || (pw >= 91 && pw <= 291);
    const bool cm = (pw == 89) || (pw == 90) || (pw >= 292);
    const float scale = is_opt ? optor_lamda[0] * (om ? 1.f : 0.f)
                               : const_lamda[0] * (cm ? 1.f : 0.f);

    const int*   vals  = is_opt ? optor_vals  : const_vals;
    const float* dists = is_opt ? optor_dists : const_dists;
    const float  temp  = is_opt ? optor_temp[0] : const_temp[0];

    const float sv = -dists[row * Kc + k] / temp;
    float mx = sv;
#pragma unroll
    for (int off = 16; off > 0; off >>= 1)     // stays within each 32-lane half
        mx = fmaxf(mx, __shfl_xor(mx, off));
    const float e = __expf(sv - mx);
    float sm = e;
#pragma unroll
    for (int off = 16; off > 0; off >>= 1)
        sm += __shfl_xor(sm, off);
    const float w = e / sm;

    if (scale != 0.f)
        atomicAdd(out + (size_t)row * Vc + vals[row * Kc + k], scale * w);
}

extern "C" void kernel_launch(void* const* d_in, const int* in_sizes, int n_in,
                              void* d_out, int out_size, void* d_ws, size_t ws_size,
                              hipStream_t stream) {
    const float* logit       = (const float*)d_in[0];
    const int*   optor_vals  = (const int*)  d_in[1];
    const float* optor_dists = (const float*)d_in[2];
    const int*   const_vals  = (const int*)  d_in[3];
    const float* const_dists = (const float*)d_in[4];
    const int*   prev_words  = (const int*)  d_in[5];
    const float* optor_lamda = (const float*)d_in[6];
    const float* const_lamda = (const float*)d_in[7];
    const float* optor_temp  = (const float*)d_in[8];
    const float* const_temp  = (const float*)d_in[9];
    float* out = (float*)d_out;
    float* ws  = (float*)d_ws;   // 2 floats per row = 8 KB

    knn_reduce_kernel<<<ROWS, NTA, 0, stream>>>(
        logit, prev_words, optor_lamda, const_lamda, ws);

    knn_map_kernel<<<dim3(ROWS, CHUNKS), NTB, 0, stream>>>(logit, ws, out);

    knn_scatter_kernel<<<ROWS, 64, 0, stream>>>(
        optor_vals, optor_dists, const_vals, const_dists, prev_words,
        optor_lamda, const_lamda, optor_temp, const_temp, out);
}